// Round 2
// baseline (204.460 us; speedup 1.0000x reference)
//
#include <hip/hip_runtime.h>
#include <hip/hip_bf16.h>

#define BATCH 8
#define NN    2048
#define DD    64
#define BN    (BATCH * NN)          // 16384 rows
#define MWORDS 68                   // padded words per mask row in LDS

typedef __attribute__((ext_vector_type(8))) short bf16x8;
typedef __attribute__((ext_vector_type(4))) float f32x4;

// pack two fp32 into one dword of two RNE-rounded bf16 (lo, hi) — manual path (kA)
static __device__ __forceinline__ unsigned f2bf_pk(float lo, float hi) {
  unsigned ul = __float_as_uint(lo);
  unsigned uh = __float_as_uint(hi);
  ul = (ul + 0x7fffu + ((ul >> 16) & 1u)) >> 16;
  uh = (uh + 0x7fffu + ((uh >> 16) & 1u)) & 0xffff0000u;
  return ul | uh;
}

// single-instruction RNE pack (gfx950): D[15:0]=bf16(lo), D[31:16]=bf16(hi)
static __device__ __forceinline__ unsigned cvtpk(float lo, float hi) {
  unsigned r;
  asm("v_cvt_pk_bf16_f32 %0, %1, %2" : "=v"(r) : "v"(lo), "v"(hi));
  return r;
}

// -------------------------------------------------------------------------
// Kernel A (dual role) — UNCHANGED (adj read is at its compulsory-bytes floor):
//  blocks 0..511    : k1 = relu(h@W), t1, t2, frag-native bf16 hwT
//  blocks 512..4607 : kpack = adj -> bitmasks (row-major coalesced, root-skip)
// -------------------------------------------------------------------------
__global__ __launch_bounds__(256) void kA(
    const float* __restrict__ h, const float* __restrict__ W,
    const float* __restrict__ a1, const float* __restrict__ a2,
    const int* __restrict__ adj, const float* __restrict__ h_root,
    unsigned short* __restrict__ hwT, float* __restrict__ t1,
    float* __restrict__ t2, unsigned* __restrict__ masks) {
  if (blockIdx.x >= 512) {
    const int row  = (blockIdx.x - 512) * 4 + (threadIdx.x >> 6);
    const int lane = threadIdx.x & 63;
    if (h_root[row] <= 0.f) return;        // wave-uniform skip
    const int* ap = adj + (size_t)row * NN + lane * 32;
    unsigned word = 0;
#pragma unroll
    for (int i = 0; i < 8; ++i) {
      int4 v = *reinterpret_cast<const int4*>(ap + i * 4);
      word |= (v.x > 0 ? 1u : 0u) << (i * 4 + 0);
      word |= (v.y > 0 ? 1u : 0u) << (i * 4 + 1);
      word |= (v.z > 0 ? 1u : 0u) << (i * 4 + 2);
      word |= (v.w > 0 ? 1u : 0u) << (i * 4 + 3);
    }
    masks[(size_t)row * 64 + lane] = word;
    return;
  }

  // ---- k1 role: 512 blocks, 32 rows each ----
  __shared__ float ht[64 * 36];
  __shared__ float Ws[64 * 64];
  __shared__ unsigned short bt[64 * 40];

  const int t  = threadIdx.x;
  const int r0 = blockIdx.x * 32;

#pragma unroll
  for (int r = 0; r < 4; ++r) {
    int f = t + 256 * r;
    reinterpret_cast<float4*>(Ws)[f] = reinterpret_cast<const float4*>(W)[f];
  }
#pragma unroll
  for (int r = 0; r < 2; ++r) {
    int f = t + 256 * r;
    int i = f >> 4, j4 = f & 15;
    float4 v = reinterpret_cast<const float4*>(h + (size_t)(r0 + i) * DD)[j4];
    ht[(4 * j4 + 0) * 36 + i] = v.x;
    ht[(4 * j4 + 1) * 36 + i] = v.y;
    ht[(4 * j4 + 2) * 36 + i] = v.z;
    ht[(4 * j4 + 3) * 36 + i] = v.w;
  }
  __syncthreads();

  const int trow = t >> 4, kcol = t & 15;
  float4 acc0 = make_float4(0.f, 0.f, 0.f, 0.f);
  float4 acc1 = make_float4(0.f, 0.f, 0.f, 0.f);

#pragma unroll 8
  for (int j = 0; j < 64; ++j) {
    float2 hv = *reinterpret_cast<const float2*>(&ht[j * 36 + 2 * trow]);
    float4 wv = reinterpret_cast<const float4*>(Ws)[j * 16 + kcol];
    acc0.x = fmaf(hv.x, wv.x, acc0.x); acc0.y = fmaf(hv.x, wv.y, acc0.y);
    acc0.z = fmaf(hv.x, wv.z, acc0.z); acc0.w = fmaf(hv.x, wv.w, acc0.w);
    acc1.x = fmaf(hv.y, wv.x, acc1.x); acc1.y = fmaf(hv.y, wv.y, acc1.y);
    acc1.z = fmaf(hv.y, wv.z, acc1.z); acc1.w = fmaf(hv.y, wv.w, acc1.w);
  }

  acc0.x = fmaxf(acc0.x, 0.f); acc0.y = fmaxf(acc0.y, 0.f);
  acc0.z = fmaxf(acc0.z, 0.f); acc0.w = fmaxf(acc0.w, 0.f);
  acc1.x = fmaxf(acc1.x, 0.f); acc1.y = fmaxf(acc1.y, 0.f);
  acc1.z = fmaxf(acc1.z, 0.f); acc1.w = fmaxf(acc1.w, 0.f);

  float4 a1v = reinterpret_cast<const float4*>(a1)[kcol];
  float4 a2v = reinterpret_cast<const float4*>(a2)[kcol];
  float s1_0 = acc0.x * a1v.x + acc0.y * a1v.y + acc0.z * a1v.z + acc0.w * a1v.w;
  float s1_1 = acc1.x * a1v.x + acc1.y * a1v.y + acc1.z * a1v.z + acc1.w * a1v.w;
  float s2_0 = acc0.x * a2v.x + acc0.y * a2v.y + acc0.z * a2v.z + acc0.w * a2v.w;
  float s2_1 = acc1.x * a2v.x + acc1.y * a2v.y + acc1.z * a2v.z + acc1.w * a2v.w;
#pragma unroll
  for (int mm = 1; mm <= 8; mm <<= 1) {
    s1_0 += __shfl_xor(s1_0, mm, 64);
    s1_1 += __shfl_xor(s1_1, mm, 64);
    s2_0 += __shfl_xor(s2_0, mm, 64);
    s2_1 += __shfl_xor(s2_1, mm, 64);
  }
  {
    int row = r0 + 2 * trow;
    if (kcol == 0) {
      t1[row] = s1_0; t1[row + 1] = s1_1;
      t2[row] = s2_0; t2[row + 1] = s2_1;
    }
  }

  {
    const float* a0 = &acc0.x;
    const float* a1p = &acc1.x;
#pragma unroll
    for (int c = 0; c < 4; ++c) {
      int k = 4 * kcol + c;
      *reinterpret_cast<unsigned*>(&bt[k * 40 + 2 * trow]) = f2bf_pk(a0[c], a1p[c]);
    }
  }
  __syncthreads();
  {
    int k = t >> 2, jp = t & 3;
    int g = k >> 4, n = k & 15;
    int bb = r0 >> 11;
    int jb = r0 & (NN - 1);
    int ks = jb >> 5;
    size_t base = ((((size_t)bb * (NN / 32) + ks) * 4 + g) * 64 + (jp * 16 + n)) * 8;
    *reinterpret_cast<int4*>(hwT + base) = *reinterpret_cast<const int4*>(&bt[k * 40 + jp * 8]);
  }
}

// -------------------------------------------------------------------------
// Kernel 2 v2: 32 rows per block (grid 512). Each wave builds TWO A-frags
// (rows m and m+16) per B-frag load -> 8 MFMAs/iter, HALVING the L2
// B-fragment traffic (268 MB -> 134 MB), which the cycle model says was the
// k2 bottleneck. A-frag bf16 pack via single v_cvt_pk_bf16_f32 (RNE,
// bit-identical to manual path). unroll 2 + launch_bounds(256,2) gives the
// scheduler VGPR room to pipeline B-loads across iterations (2 blocks/CU
// from grid; LDS 52 KB). Inactive rows compute bounded garbage, discarded
// by root-select.
// -------------------------------------------------------------------------
__global__ __launch_bounds__(256, 2) void k2_attn(
    const unsigned short* __restrict__ hwT, const unsigned* __restrict__ masks,
    const float* __restrict__ t1, const float* __restrict__ t2,
    const float* __restrict__ h, const float* __restrict__ h_root,
    float* __restrict__ out) {
  __shared__ unsigned maskS[32 * MWORDS];   // 8.7 KB
  __shared__ float t2s[NN];                 // 8 KB
  __shared__ float os[4][32][68];           // 34.8 KB
  __shared__ float denos[4][32];

  const int t    = threadIdx.x;
  const int b    = blockIdx.x & 7;           // XCD-aware: batch == XCD
  const int i0   = (blockIdx.x >> 3) * 32;   // block's 32-row tile
  const int w    = t >> 6;                   // wave id = j quarter
  const int lane = t & 63;
  const int m    = lane & 15;
  const int quad = lane >> 4;
  const int rowbase = b * NN + i0;

  // stage t2 row-block (coalesced)
#pragma unroll
  for (int r = 0; r < 2; ++r)
    reinterpret_cast<float4*>(t2s)[t + 256 * r] =
        reinterpret_cast<const float4*>(t2 + b * NN)[t + 256 * r];

  // stage masks: 32 rows x 64 words = 8 KB contiguous, two int4/thread
#pragma unroll
  for (int r = 0; r < 2; ++r) {
    int idx = t + 256 * r;                   // 0..511
    int row = idx >> 4, w4 = idx & 15;
    int4 mv = *reinterpret_cast<const int4*>(
        masks + ((size_t)(rowbase + row)) * 64 + w4 * 4);
    *reinterpret_cast<int4*>(&maskS[row * MWORDS + w4 * 4]) = mv;
  }
  __syncthreads();

  // compute: wave w owns ks = w*16 .. w*16+15 (512 j) for all 32 rows
  const float t1v0 = t1[rowbase + m];
  const float t1v1 = t1[rowbase + 16 + m];
  const int ks0 = w * 16;

  f32x4 acc[4][2];
#pragma unroll
  for (int g = 0; g < 4; ++g) {
    acc[g][0] = (f32x4){0.f, 0.f, 0.f, 0.f};
    acc[g][1] = (f32x4){0.f, 0.f, 0.f, 0.f};
  }
  float den0 = 0.f, den1 = 0.f;

#pragma unroll 2
  for (int kk = 0; kk < 16; ++kk) {
    const int ks = ks0 + kk;

    // B-frags: lane-contiguous 1 KB per load (L2-resident hwT), shared by both tiles
    const unsigned short* bp =
        hwT + ((((size_t)b * (NN / 32) + ks) * 4) * 64 + lane) * 8;
    bf16x8 B0 = *reinterpret_cast<const bf16x8*>(bp);
    bf16x8 B1 = *reinterpret_cast<const bf16x8*>(bp + 512);
    bf16x8 B2 = *reinterpret_cast<const bf16x8*>(bp + 1024);
    bf16x8 B3 = *reinterpret_cast<const bf16x8*>(bp + 1536);

    const float* t2p = &t2s[ks * 32 + quad * 8];
    float4 e0 = *reinterpret_cast<const float4*>(t2p);
    float4 e1 = *reinterpret_cast<const float4*>(t2p + 4);

    const unsigned ma = maskS[m * MWORDS + ks] >> (quad * 8);
    const unsigned mb = maskS[(m + 16) * MWORDS + ks] >> (quad * 8);

    // tile 0: row m
    float p0 = (ma & 1u)   ? __expf(fmaxf(t1v0 + e0.x, 0.f)) : 1.f;
    float p1 = (ma & 2u)   ? __expf(fmaxf(t1v0 + e0.y, 0.f)) : 1.f;
    float p2 = (ma & 4u)   ? __expf(fmaxf(t1v0 + e0.z, 0.f)) : 1.f;
    float p3 = (ma & 8u)   ? __expf(fmaxf(t1v0 + e0.w, 0.f)) : 1.f;
    float p4 = (ma & 16u)  ? __expf(fmaxf(t1v0 + e1.x, 0.f)) : 1.f;
    float p5 = (ma & 32u)  ? __expf(fmaxf(t1v0 + e1.y, 0.f)) : 1.f;
    float p6 = (ma & 64u)  ? __expf(fmaxf(t1v0 + e1.z, 0.f)) : 1.f;
    float p7 = (ma & 128u) ? __expf(fmaxf(t1v0 + e1.w, 0.f)) : 1.f;
    den0 += ((p0 + p1) + (p2 + p3)) + ((p4 + p5) + (p6 + p7));

    // tile 1: row m+16
    float q0 = (mb & 1u)   ? __expf(fmaxf(t1v1 + e0.x, 0.f)) : 1.f;
    float q1 = (mb & 2u)   ? __expf(fmaxf(t1v1 + e0.y, 0.f)) : 1.f;
    float q2 = (mb & 4u)   ? __expf(fmaxf(t1v1 + e0.z, 0.f)) : 1.f;
    float q3 = (mb & 8u)   ? __expf(fmaxf(t1v1 + e0.w, 0.f)) : 1.f;
    float q4 = (mb & 16u)  ? __expf(fmaxf(t1v1 + e1.x, 0.f)) : 1.f;
    float q5 = (mb & 32u)  ? __expf(fmaxf(t1v1 + e1.y, 0.f)) : 1.f;
    float q6 = (mb & 64u)  ? __expf(fmaxf(t1v1 + e1.z, 0.f)) : 1.f;
    float q7 = (mb & 128u) ? __expf(fmaxf(t1v1 + e1.w, 0.f)) : 1.f;
    den1 += ((q0 + q1) + (q2 + q3)) + ((q4 + q5) + (q6 + q7));

    union { bf16x8 v; unsigned u[4]; } Af0, Af1;
    Af0.u[0] = cvtpk(p0, p1); Af0.u[1] = cvtpk(p2, p3);
    Af0.u[2] = cvtpk(p4, p5); Af0.u[3] = cvtpk(p6, p7);
    Af1.u[0] = cvtpk(q0, q1); Af1.u[1] = cvtpk(q2, q3);
    Af1.u[2] = cvtpk(q4, q5); Af1.u[3] = cvtpk(q6, q7);

    acc[0][0] = __builtin_amdgcn_mfma_f32_16x16x32_bf16(Af0.v, B0, acc[0][0], 0, 0, 0);
    acc[1][0] = __builtin_amdgcn_mfma_f32_16x16x32_bf16(Af0.v, B1, acc[1][0], 0, 0, 0);
    acc[2][0] = __builtin_amdgcn_mfma_f32_16x16x32_bf16(Af0.v, B2, acc[2][0], 0, 0, 0);
    acc[3][0] = __builtin_amdgcn_mfma_f32_16x16x32_bf16(Af0.v, B3, acc[3][0], 0, 0, 0);
    acc[0][1] = __builtin_amdgcn_mfma_f32_16x16x32_bf16(Af1.v, B0, acc[0][1], 0, 0, 0);
    acc[1][1] = __builtin_amdgcn_mfma_f32_16x16x32_bf16(Af1.v, B1, acc[1][1], 0, 0, 0);
    acc[2][1] = __builtin_amdgcn_mfma_f32_16x16x32_bf16(Af1.v, B2, acc[2][1], 0, 0, 0);
    acc[3][1] = __builtin_amdgcn_mfma_f32_16x16x32_bf16(Af1.v, B3, acc[3][1], 0, 0, 0);
  }

  // den: quads own disjoint j subsets -> reduce over quads in-wave
  den0 += __shfl_xor(den0, 16, 64);
  den0 += __shfl_xor(den0, 32, 64);
  den1 += __shfl_xor(den1, 16, 64);
  den1 += __shfl_xor(den1, 32, 64);
  if (quad == 0) { denos[w][m] = den0; denos[w][16 + m] = den1; }

  // per-wave partial C(32x64) into LDS
#pragma unroll
  for (int g = 0; g < 4; ++g)
#pragma unroll
    for (int r = 0; r < 4; ++r) {
      os[w][quad * 4 + r][g * 16 + m]      = acc[g][0][r];
      os[w][16 + quad * 4 + r][g * 16 + m] = acc[g][1][r];
    }
  __syncthreads();

  // block reduce over the 4 waves + normalize + root-select + store
#pragma unroll
  for (int rr = 0; rr < 2; ++rr) {
    const int i = (t >> 4) + 16 * rr, k4 = t & 15;
    float4 a = make_float4(0.f, 0.f, 0.f, 0.f);
    float d = 0.f;
#pragma unroll
    for (int ww = 0; ww < 4; ++ww) {
      float4 p = *reinterpret_cast<const float4*>(&os[ww][i][k4 * 4]);
      a.x += p.x; a.y += p.y; a.z += p.z; a.w += p.w;
      d += denos[ww][i];
    }
    const size_t row = (size_t)rowbase + i;
    float4 res;
    if (h_root[row] > 0.f) {
      const float inv = 1.f / d;
      res.x = a.x * inv; res.y = a.y * inv; res.z = a.z * inv; res.w = a.w * inv;
    } else {
      res = reinterpret_cast<const float4*>(h + row * DD)[k4];
    }
    reinterpret_cast<float4*>(out + row * DD)[k4] = res;
  }
}

extern "C" void kernel_launch(void* const* d_in, const int* in_sizes, int n_in,
                              void* d_out, int out_size, void* d_ws, size_t ws_size,
                              hipStream_t stream) {
  const float* h      = (const float*)d_in[0];
  const int*   adj    = (const int*)d_in[1];
  const float* h_root = (const float*)d_in[2];
  const float* W      = (const float*)d_in[3];
  const float* a1     = (const float*)d_in[4];
  const float* a2     = (const float*)d_in[5];
  float* out = (float*)d_out;

  // ws: hwT (bf16 frag-native, BN*DD) | t1 | t2 | masks (BN*64 u32)
  unsigned short* hwT = (unsigned short*)d_ws;
  float* t1 = (float*)(hwT + (size_t)BN * DD);
  float* t2 = t1 + BN;
  unsigned* masks = (unsigned*)(t2 + BN);

  kA<<<512 + BN / 4, 256, 0, stream>>>(h, W, a1, a2, adj, h_root, hwT, t1, t2, masks);
  k2_attn<<<BATCH * (NN / 32), 256, 0, stream>>>(hwT, masks, t1, t2, h, h_root, out);
}